// Round 2
// baseline (74.687 us; speedup 1.0000x reference)
//
#include <hip/hip_runtime.h>
#include <math.h>

#define NN 768
#define DD 128
#define XC 64     // neighbor rows cached in LDS (binomial(768,0.04): mean~31, max~55)
#define MAXN 128  // compaction capacity: >2x observed max degree

// Fully fused, latency-restructured:
//  - all independent global loads issued before the first barrier
//  - pair math merged into the dot phase (group leaders), killing the
//    dots/y2s/wrs LDS round-trip and one __syncthreads
//  - xi[] LDS removed (row-i fragments load from global, L1-broadcast)
//  - u / ov stay in registers across the epilogue
__global__ __launch_bounds__(256) void hypagg_fused(
        const float* __restrict__ x, const float* __restrict__ adj,
        const float* __restrict__ att_w, const float* __restrict__ att_b,
        float* __restrict__ out) {
    __shared__ float  xcache[XC][DD];      // 32 KB neighbor-row cache
    __shared__ int    list[MAXN];
    __shared__ float  aval[MAXN];
    __shared__ float  bco[MAXN];
    __shared__ double upart[DD];           // odd-half aggregation partials
    __shared__ int    counter;
    __shared__ double s_x2i, s_sLi;
    __shared__ double cpart[4];
    __shared__ double epart[2][3];

    const int i = blockIdx.x, t = threadIdx.x;
    const int wid = t >> 6, lane = t & 63;
    const int g = t >> 4, gl = t & 15;     // 16-lane dot groups

    // ---- issue ALL independent global loads up front (latency hides under syncs) ----
    float4 adjv = make_float4(0.f, 0.f, 0.f, 0.f);
    if (t >= 64) adjv = ((const float4*)(adj + (size_t)i * NN))[t - 64];
    float xv = 0.0f;
    if (t < DD) xv = x[(size_t)i * DD + t];
    const float4 xa = ((const float4*)(x + (size_t)i * DD))[gl];        // row-i frag
    const float4 xb = ((const float4*)(x + (size_t)i * DD))[16 + gl];
    const float4 wa = ((const float4*)(att_w + DD))[gl];                // wr frag
    const float4 wb = ((const float4*)(att_w + DD))[16 + gl];
    const double b0 = (double)att_b[0];

    if (t == 0) counter = 0;
    __syncthreads();   // orders counter=0 only; loads above remain in flight

    // ---- waves 1..3: compact nonzero columns of adj row i ----
    // ---- wave 0 (concurrently): own-row scalars x2_i, sL_i ----
    if (t >= 64) {
        int m = (adjv.x != 0.0f) + (adjv.y != 0.0f) + (adjv.z != 0.0f) + (adjv.w != 0.0f);
        if (m) {
            int base = atomicAdd(&counter, m);
            int j = 4 * (t - 64);
            if (adjv.x != 0.0f && base < MAXN) { list[base] = j;     aval[base] = adjv.x; ++base; }
            if (adjv.y != 0.0f && base < MAXN) { list[base] = j + 1; aval[base] = adjv.y; ++base; }
            if (adjv.z != 0.0f && base < MAXN) { list[base] = j + 2; aval[base] = adjv.z; ++base; }
            if (adjv.w != 0.0f && base < MAXN) { list[base] = j + 3; aval[base] = adjv.w; ++base; }
        }
    } else {
        const float2 xv2 = ((const float2*)(x + (size_t)i * DD))[lane];
        const float2 wl2 = ((const float2*)att_w)[lane];
        double dx2 = (double)xv2.x * xv2.x + (double)xv2.y * xv2.y;
        double dl  = (double)xv2.x * wl2.x + (double)xv2.y * wl2.y;
        #pragma unroll
        for (int o = 32; o > 0; o >>= 1) {
            dx2 += __shfl_down(dx2, o, 64);
            dl  += __shfl_down(dl,  o, 64);
        }
        if (lane == 0) {
            double r  = sqrt(dx2);
            double g0 = atanh(fmin(r, 1.0 - 1e-7)) / fmax(r, 1e-15);
            s_x2i = dx2;
            s_sLi = g0 * dl;
        }
    }
    __syncthreads();   // list/aval + s_x2i/s_sLi ready
    const int n = (counter < MAXN) ? counter : MAXN;

    // ---- dot phase + fused pair math: one 16-lane group per neighbor ----
    double asum = 0.0;
    {
        const double x2i = s_x2i, sLi = s_sLi;
        const double beta = 1.0 - x2i;
        const double factor = fmax(beta, 1e-15);   // 2/(sqrt_c*lambda_i)
        for (int k = g; k < n; k += 16) {
            const float4* xj4 = (const float4*)(x + (size_t)list[k] * DD);
            float4 a = xj4[gl];        // elems gl*4 .. gl*4+3   (contiguous 256B/group)
            float4 b = xj4[16 + gl];   // elems 64+gl*4 ..
            if (k < XC) {
                ((float4*)xcache[k])[gl]      = a;
                ((float4*)xcache[k])[16 + gl] = b;
            }
            double dd = (double)xa.x * a.x + (double)xa.y * a.y
                      + (double)xa.z * a.z + (double)xa.w * a.w
                      + (double)xb.x * b.x + (double)xb.y * b.y
                      + (double)xb.z * b.z + (double)xb.w * b.w;
            double yy = (double)a.x * a.x + (double)a.y * a.y
                      + (double)a.z * a.z + (double)a.w * a.w
                      + (double)b.x * b.x + (double)b.y * b.y
                      + (double)b.z * b.z + (double)b.w * b.w;
            double ww = (double)wa.x * a.x + (double)wa.y * a.y
                      + (double)wa.z * a.z + (double)wa.w * a.w
                      + (double)wb.x * b.x + (double)wb.y * b.y
                      + (double)wb.z * b.z + (double)wb.w * b.w;
            #pragma unroll
            for (int o = 8; o > 0; o >>= 1) {
                dd += __shfl_down(dd, o, 16);
                yy += __shfl_down(yy, o, 16);
                ww += __shfl_down(ww, o, 16);
            }
            if (gl == 0) {     // leader: full scalar pair chain in-register
                double dot = dd;
                double y2  = yy;
                double ry  = sqrt(y2);
                double g0j = atanh(fmin(ry, 1.0 - 1e-7)) / fmax(ry, 1e-15);
                double z   = sLi + g0j * ww + b0;
                double w   = (double)aval[k] / (1.0 + exp(-z));   // sigmoid * adj
                double alpha  = 1.0 - 2.0 * dot + y2;
                double denomc = fmax(1.0 - 2.0 * dot + x2i * y2, 1e-15);
                double sn2 = (alpha * alpha * x2i - 2.0 * alpha * beta * dot + beta * beta * y2)
                             / (denomc * denomc);
                double sn  = fmax(sqrt(fmax(sn2, 0.0)), 1e-15);
                double gg  = atanh(fmin(sn, 1.0 - 1e-7)) / sn;
                double common = w * factor * gg / denomc;
                asum -= common * alpha;              // coefficient on x_i
                bco[k] = (float)(common * beta);     // coefficient on x_j
            }
        }
    }
    #pragma unroll
    for (int o = 32; o > 0; o >>= 1) asum += __shfl_down(asum, o, 64);
    if (lane == 0) cpart[wid] = asum;
    __syncthreads();   // bco + cpart ready

    // ---- aggregation: even k on t<128, odd k on t>=128, combine via LDS ----
    double u = 0.0;
    {
        const int d = t & (DD - 1);
        const int h = t >> 7;              // 0: even ks + final, 1: odd ks
        double p = 0.0;
        const int nc = (n < XC) ? n : XC;
        for (int k = h; k < nc; k += 2) p += (double)bco[k] * (double)xcache[k][d];
        for (int k = XC + h; k < n; k += 2) p += (double)bco[k] * (double)x[(size_t)list[k] * DD + d];
        if (h == 1) upart[d] = p;
        __syncthreads();
        if (t < DD) {
            const double rowA = cpart[0] + cpart[1] + cpart[2] + cpart[3];
            u = rowA * (double)xv + p + upart[d];
            double p_un2 = u * u;
            double p_xu  = (double)xv * u;
            #pragma unroll
            for (int o = 32; o > 0; o >>= 1) {
                p_un2 += __shfl_down(p_un2, o, 64);
                p_xu  += __shfl_down(p_xu,  o, 64);
            }
            if (lane == 0) { epart[wid][0] = p_un2; epart[wid][1] = p_xu; }
        }
    }
    __syncthreads();

    // ---- expmap(u, x_i), mobius_add(x_i, second) — u stays in-register ----
    double ov = 0.0;
    if (t < DD) {
        double un2 = epart[0][0] + epart[1][0];
        double xu  = epart[0][1] + epart[1][1];
        double x2i = s_x2i;
        double lamfac = fmax(1.0 - x2i, 1e-15);         // 2/lambda_i
        double un = fmax(sqrt(un2), 1e-15);
        double th = tanh(un / lamfac);
        double s  = th / un;                            // second = s*u
        double y2 = s * s * un2;
        double xy = s * xu;
        double c1 = 1.0 + 2.0 * xy + y2;
        double c2 = 1.0 - x2i;
        double den = fmax(1.0 + 2.0 * xy + x2i * y2, 1e-15);
        ov = (c1 * (double)xv + c2 * s * u) / den;
        double p_on2 = ov * ov;
        #pragma unroll
        for (int o = 32; o > 0; o >>= 1) p_on2 += __shfl_down(p_on2, o, 64);
        if (lane == 0) epart[wid][2] = p_on2;
    }
    __syncthreads();

    // ---- proj + store ----
    if (t < DD) {
        double on2 = epart[0][2] + epart[1][2];
        double on  = fmax(sqrt(on2), 1e-15);
        const double maxn = 1.0 - 4e-3;                 // (1-PROJ_EPS)/sqrt(c)
        double scale = (on > maxn) ? (maxn / on) : 1.0;
        out[i * DD + t] = (float)(ov * scale);
    }
}

extern "C" void kernel_launch(void* const* d_in, const int* in_sizes, int n_in,
                              void* d_out, int out_size, void* d_ws, size_t ws_size,
                              hipStream_t stream) {
    const float* x     = (const float*)d_in[0];
    const float* adj   = (const float*)d_in[1];
    const float* att_w = (const float*)d_in[2];
    const float* att_b = (const float*)d_in[3];
    float* out = (float*)d_out;
    (void)d_ws; (void)ws_size;   // workspace intentionally unused

    hypagg_fused<<<NN, 256, 0, stream>>>(x, adj, att_w, att_b, out);
}

// Round 3
// 72.074 us; speedup vs baseline: 1.0363x; 1.0363x over previous
//
#include <hip/hip_runtime.h>
#include <math.h>

#define NN 768
#define DD 128
#define MAXN 96   // degree capacity: mean~31, sd~5.4, observed max ~55; 96 = mean+12sd

// One wave per row. Block = 64 threads = 1 wave, so __syncthreads() is just a
// waitcnt (no inter-wave rendezvous). All cross-thread traffic is shuffles or a
// 3.5 KB wave-private LDS strip. No atomics, no xcache (x is L2-resident).
__global__ __launch_bounds__(64) void hypagg_wave(
        const float* __restrict__ x, const float* __restrict__ adj,
        const float* __restrict__ att_w, const float* __restrict__ att_b,
        float* __restrict__ out) {
    __shared__ int    list[MAXN];
    __shared__ float  aval[MAXN];
    __shared__ double dots[MAXN];   // <x_i, x_j>
    __shared__ double y2s[MAXN];    // <x_j, x_j>
    __shared__ double wrs[MAXN];    // <x_j, wr>
    __shared__ float  bco[MAXN];

    const int i    = blockIdx.x;
    const int lane = threadIdx.x;
    const int gl   = lane & 15;     // lane in 16-lane dot group
    const int g    = lane >> 4;     // group 0..3

    // ---- hoist ALL independent global loads ----
    const float4 adjv0 = ((const float4*)(adj + (size_t)i * NN))[lane];
    const float4 adjv1 = ((const float4*)(adj + (size_t)i * NN))[lane + 64];
    const float4 adjv2 = ((const float4*)(adj + (size_t)i * NN))[lane + 128];
    const float2 xv2 = ((const float2*)(x + (size_t)i * DD))[lane];   // dims 2l, 2l+1
    const float2 wl2 = ((const float2*)att_w)[lane];
    const float4 xa  = ((const float4*)(x + (size_t)i * DD))[gl];     // dot-frag of row i
    const float4 xb  = ((const float4*)(x + (size_t)i * DD))[16 + gl];
    const float4 wa  = ((const float4*)(att_w + DD))[gl];             // wr frag
    const float4 wb  = ((const float4*)(att_w + DD))[16 + gl];
    const double b0  = (double)att_b[0];

    // ---- row scalars x2_i, sL_i: butterfly reduce, all lanes get totals ----
    double dx2 = (double)xv2.x * xv2.x + (double)xv2.y * xv2.y;
    double dl  = (double)xv2.x * wl2.x + (double)xv2.y * wl2.y;
    #pragma unroll
    for (int o = 32; o > 0; o >>= 1) {
        dx2 += __shfl_xor(dx2, o, 64);
        dl  += __shfl_xor(dl,  o, 64);
    }
    const double x2i = dx2;
    {
        // fold g0_i into sL_i (all lanes redundantly; uniform)
    }
    double r_  = sqrt(dx2);
    double g0i = atanh(fmin(r_, 1.0 - 1e-7)) / fmax(r_, 1e-15);
    const double sLi = g0i * dl;

    // ---- compact adj row: 12 ballot rounds, no atomics ----
    int n = 0;
    {
        const unsigned long long below = (lane == 0) ? 0ull : (~0ull >> (64 - lane));
        const float vals[12] = {adjv0.x, adjv0.y, adjv0.z, adjv0.w,
                                adjv1.x, adjv1.y, adjv1.z, adjv1.w,
                                adjv2.x, adjv2.y, adjv2.z, adjv2.w};
        #pragma unroll
        for (int rnd = 0; rnd < 12; ++rnd) {
            float v = vals[rnd];
            unsigned long long m = __ballot(v != 0.0f);
            if (v != 0.0f) {
                int pos = n + __popcll(m & below);
                if (pos < MAXN) {
                    list[pos] = 4 * ((rnd >> 2) * 64 + lane) + (rnd & 3);
                    aval[pos] = v;
                }
            }
            n += __popcll(m);
        }
        if (n > MAXN) n = MAXN;
    }
    __syncthreads();   // 1-wave block: compiles to waitcnt, no real barrier

    // ---- dot phase: one 16-lane group per neighbor, 8 elems/lane ----
    for (int k = g; k < n; k += 4) {
        const float4* xj4 = (const float4*)(x + (size_t)list[k] * DD);
        float4 a = xj4[gl];        // elems 4gl..4gl+3 (64B contiguous per group)
        float4 b = xj4[16 + gl];   // elems 64+4gl..
        double dd = (double)xa.x * a.x + (double)xa.y * a.y
                  + (double)xa.z * a.z + (double)xa.w * a.w
                  + (double)xb.x * b.x + (double)xb.y * b.y
                  + (double)xb.z * b.z + (double)xb.w * b.w;
        double yy = (double)a.x * a.x + (double)a.y * a.y
                  + (double)a.z * a.z + (double)a.w * a.w
                  + (double)b.x * b.x + (double)b.y * b.y
                  + (double)b.z * b.z + (double)b.w * b.w;
        double ww = (double)wa.x * a.x + (double)wa.y * a.y
                  + (double)wa.z * a.z + (double)wa.w * a.w
                  + (double)wb.x * b.x + (double)wb.y * b.y
                  + (double)wb.z * b.z + (double)wb.w * b.w;
        #pragma unroll
        for (int o = 8; o > 0; o >>= 1) {
            dd += __shfl_down(dd, o, 16);
            yy += __shfl_down(yy, o, 16);
            ww += __shfl_down(ww, o, 16);
        }
        if (gl == 0) { dots[k] = dd; y2s[k] = yy; wrs[k] = ww; }
    }
    __syncthreads();

    // ---- pair math: ONE neighbor per lane, fully parallel (n <= 55 < 64) ----
    double asum = 0.0;
    {
        const double beta   = 1.0 - x2i;
        const double factor = fmax(beta, 1e-15);   // 2/(sqrt_c*lambda_i)
        for (int k = lane; k < n; k += 64) {
            double dot = dots[k];
            double y2  = y2s[k];
            double ww  = wrs[k];
            double ry  = sqrt(y2);
            double g0j = atanh(fmin(ry, 1.0 - 1e-7)) / fmax(ry, 1e-15);
            double z   = sLi + g0j * ww + b0;
            double w   = (double)aval[k] / (1.0 + exp(-z));   // sigmoid * adj
            double alpha  = 1.0 - 2.0 * dot + y2;
            double denomc = fmax(1.0 - 2.0 * dot + x2i * y2, 1e-15);
            double sn2 = (alpha * alpha * x2i - 2.0 * alpha * beta * dot + beta * beta * y2)
                         / (denomc * denomc);
            double sn  = fmax(sqrt(fmax(sn2, 0.0)), 1e-15);
            double gg  = atanh(fmin(sn, 1.0 - 1e-7)) / sn;
            double common = w * factor * gg / denomc;
            asum -= common * alpha;              // coefficient on x_i
            bco[k] = (float)(common * beta);     // coefficient on x_j
        }
    }
    #pragma unroll
    for (int o = 32; o > 0; o >>= 1) asum += __shfl_xor(asum, o, 64);
    __syncthreads();   // bco visible to all lanes

    // ---- aggregation: each lane owns dims (2l, 2l+1); x_j streamed from L2 ----
    double ux = asum * (double)xv2.x;
    double uy = asum * (double)xv2.y;
    #pragma unroll 4
    for (int k = 0; k < n; ++k) {
        double b = (double)bco[k];                                   // LDS broadcast
        float2 xj = ((const float2*)(x + (size_t)list[k] * DD))[lane]; // 512B coalesced
        ux += b * (double)xj.x;
        uy += b * (double)xj.y;
    }

    // ---- expmap(u, x_i) + mobius_add + proj, all in-register ----
    double p_un2 = ux * ux + uy * uy;
    double p_xu  = (double)xv2.x * ux + (double)xv2.y * uy;
    #pragma unroll
    for (int o = 32; o > 0; o >>= 1) {
        p_un2 += __shfl_xor(p_un2, o, 64);
        p_xu  += __shfl_xor(p_xu,  o, 64);
    }
    double lamfac = fmax(1.0 - x2i, 1e-15);      // 2/lambda_i
    double un = fmax(sqrt(p_un2), 1e-15);
    double th = tanh(un / lamfac);
    double s  = th / un;                         // second = s*u
    double y2 = s * s * p_un2;
    double xy = s * p_xu;
    double c1 = 1.0 + 2.0 * xy + y2;
    double c2 = 1.0 - x2i;
    double den = fmax(1.0 + 2.0 * xy + x2i * y2, 1e-15);
    double ovx = (c1 * (double)xv2.x + c2 * s * ux) / den;
    double ovy = (c1 * (double)xv2.y + c2 * s * uy) / den;

    double p_on2 = ovx * ovx + ovy * ovy;
    #pragma unroll
    for (int o = 32; o > 0; o >>= 1) p_on2 += __shfl_xor(p_on2, o, 64);
    double on = fmax(sqrt(p_on2), 1e-15);
    const double maxn_ = 1.0 - 4e-3;             // (1-PROJ_EPS)/sqrt(c)
    double scale = (on > maxn_) ? (maxn_ / on) : 1.0;
    ((float2*)(out + (size_t)i * DD))[lane] =
        make_float2((float)(ovx * scale), (float)(ovy * scale));
}

extern "C" void kernel_launch(void* const* d_in, const int* in_sizes, int n_in,
                              void* d_out, int out_size, void* d_ws, size_t ws_size,
                              hipStream_t stream) {
    const float* x     = (const float*)d_in[0];
    const float* adj   = (const float*)d_in[1];
    const float* att_w = (const float*)d_in[2];
    const float* att_b = (const float*)d_in[3];
    float* out = (float*)d_out;
    (void)d_ws; (void)ws_size;   // workspace intentionally unused

    hypagg_wave<<<NN, 64, 0, stream>>>(x, adj, att_w, att_b, out);
}

// Round 4
// 68.078 us; speedup vs baseline: 1.0971x; 1.0587x over previous
//
#include <hip/hip_runtime.h>
#include <math.h>

#define NN 768
#define DD 128
#define XC 64     // neighbor rows cached in LDS (binomial(768,0.04): mean~31, max~55)
#define MAXN 128  // compaction capacity: >2x observed max degree

// R4 = R1 phase structure (separate dot phase / parallel pair-math phase)
//    + R2's good parts (hoisted global loads, in-register epilogue)
//    + wave-0-only pair math (n<=55<64: one neighbor per lane, asum in regs)
//    + mod-4 wave-split aggregation with lane-owned dim pairs -> epilogue
//      entirely in wave 0 with butterfly shuffles.  5 barriers total.
__global__ __launch_bounds__(256) void hypagg_fused(
        const float* __restrict__ x, const float* __restrict__ adj,
        const float* __restrict__ att_w, const float* __restrict__ att_b,
        float* __restrict__ out) {
    __shared__ float  xcache[XC][DD];      // 32 KB neighbor-row cache
    __shared__ int    list[MAXN];
    __shared__ float  aval[MAXN];
    __shared__ double dots[MAXN];          // <x_i, x_j>
    __shared__ double y2s[MAXN];           // <x_j, x_j>
    __shared__ double wrs[MAXN];           // <x_j, wr>
    __shared__ float  bco[MAXN];
    __shared__ double upx[3][64];          // aggregation partials, waves 1..3
    __shared__ double upy[3][64];
    __shared__ int    counter;

    const int i = blockIdx.x, t = threadIdx.x;
    const int wid = t >> 6, lane = t & 63;
    const int g = t >> 4, gl = t & 15;     // 16-lane dot groups

    // ---- hoist ALL independent global loads (latency hides under phases 0-1) ----
    float4 adjv = make_float4(0.f, 0.f, 0.f, 0.f);
    if (t >= 64) adjv = ((const float4*)(adj + (size_t)i * NN))[t - 64];
    float2 xv2 = make_float2(0.f, 0.f), wl2 = make_float2(0.f, 0.f);
    if (t < 64) {
        xv2 = ((const float2*)(x + (size_t)i * DD))[lane];   // dims 2l, 2l+1
        wl2 = ((const float2*)att_w)[lane];
    }
    const float4 xa = ((const float4*)(x + (size_t)i * DD))[gl];   // row-i dot frag
    const float4 xb = ((const float4*)(x + (size_t)i * DD))[16 + gl];
    const float4 wa = ((const float4*)(att_w + DD))[gl];           // wr frag
    const float4 wb = ((const float4*)(att_w + DD))[16 + gl];
    const double b0 = (double)att_b[0];

    if (t == 0) counter = 0;
    __syncthreads();                                        // [1] counter ready

    // ---- waves 1..3: compact nonzero columns of adj row i ----
    // ---- wave 0 (concurrently): row scalars x2_i, sL_i (stay in registers) ----
    double x2i = 0.0, sLi = 0.0;
    if (t >= 64) {
        int m = (adjv.x != 0.0f) + (adjv.y != 0.0f) + (adjv.z != 0.0f) + (adjv.w != 0.0f);
        if (m) {
            int base = atomicAdd(&counter, m);
            int j = 4 * (t - 64);
            if (adjv.x != 0.0f && base < MAXN) { list[base] = j;     aval[base] = adjv.x; ++base; }
            if (adjv.y != 0.0f && base < MAXN) { list[base] = j + 1; aval[base] = adjv.y; ++base; }
            if (adjv.z != 0.0f && base < MAXN) { list[base] = j + 2; aval[base] = adjv.z; ++base; }
            if (adjv.w != 0.0f && base < MAXN) { list[base] = j + 3; aval[base] = adjv.w; ++base; }
        }
    } else {
        double dx2 = (double)xv2.x * xv2.x + (double)xv2.y * xv2.y;
        double dl  = (double)xv2.x * wl2.x + (double)xv2.y * wl2.y;
        #pragma unroll
        for (int o = 32; o > 0; o >>= 1) {
            dx2 += __shfl_xor(dx2, o, 64);
            dl  += __shfl_xor(dl,  o, 64);
        }
        x2i = dx2;                                   // all wave-0 lanes hold totals
        double r  = sqrt(dx2);
        double g0 = atanh(fmin(r, 1.0 - 1e-7)) / fmax(r, 1e-15);
        sLi = g0 * dl;
    }
    __syncthreads();                                        // [2] list/aval ready
    const int n = (counter < MAXN) ? counter : MAXN;

    // ---- dot phase: one 16-lane group per neighbor, 8 elems/lane ----
    for (int k = g; k < n; k += 16) {
        const float4* xj4 = (const float4*)(x + (size_t)list[k] * DD);
        float4 a = xj4[gl];        // elems 4gl..4gl+3 (contiguous 256B/group)
        float4 b = xj4[16 + gl];   // elems 64+4gl..
        if (k < XC) {
            ((float4*)xcache[k])[gl]      = a;
            ((float4*)xcache[k])[16 + gl] = b;
        }
        double dd = (double)xa.x * a.x + (double)xa.y * a.y
                  + (double)xa.z * a.z + (double)xa.w * a.w
                  + (double)xb.x * b.x + (double)xb.y * b.y
                  + (double)xb.z * b.z + (double)xb.w * b.w;
        double yy = (double)a.x * a.x + (double)a.y * a.y
                  + (double)a.z * a.z + (double)a.w * a.w
                  + (double)b.x * b.x + (double)b.y * b.y
                  + (double)b.z * b.z + (double)b.w * b.w;
        double ww = (double)wa.x * a.x + (double)wa.y * a.y
                  + (double)wa.z * a.z + (double)wa.w * a.w
                  + (double)wb.x * b.x + (double)wb.y * b.y
                  + (double)wb.z * b.z + (double)wb.w * b.w;
        #pragma unroll
        for (int o = 8; o > 0; o >>= 1) {
            dd += __shfl_down(dd, o, 16);
            yy += __shfl_down(yy, o, 16);
            ww += __shfl_down(ww, o, 16);
        }
        if (gl == 0) { dots[k] = dd; y2s[k] = yy; wrs[k] = ww; }
    }
    __syncthreads();                                        // [3] dots/xcache ready

    // ---- pair math: wave 0 only, one neighbor per lane, fully parallel ----
    double asum = 0.0;
    if (wid == 0) {
        const double beta   = 1.0 - x2i;
        const double factor = fmax(beta, 1e-15);   // 2/(sqrt_c*lambda_i)
        for (int k = lane; k < n; k += 64) {
            double dot = dots[k];
            double y2  = y2s[k];
            double ww  = wrs[k];
            double ry  = sqrt(y2);
            double g0j = atanh(fmin(ry, 1.0 - 1e-7)) / fmax(ry, 1e-15);
            double z   = sLi + g0j * ww + b0;
            double w   = (double)aval[k] / (1.0 + exp(-z));   // sigmoid * adj
            double alpha  = 1.0 - 2.0 * dot + y2;
            double denomc = fmax(1.0 - 2.0 * dot + x2i * y2, 1e-15);
            double sn2 = (alpha * alpha * x2i - 2.0 * alpha * beta * dot + beta * beta * y2)
                         / (denomc * denomc);
            double sn  = fmax(sqrt(fmax(sn2, 0.0)), 1e-15);
            double gg  = atanh(fmin(sn, 1.0 - 1e-7)) / sn;
            double common = w * factor * gg / denomc;
            asum -= common * alpha;              // coefficient on x_i
            bco[k] = (float)(common * beta);     // coefficient on x_j
        }
        #pragma unroll
        for (int o = 32; o > 0; o >>= 1) asum += __shfl_xor(asum, o, 64);
        // all wave-0 lanes now hold total asum (in-register, no LDS)
    }
    __syncthreads();                                        // [4] bco ready

    // ---- aggregation: wave w takes k = w (mod 4); lane owns dims (2l, 2l+1) ----
    double ux = 0.0, uy = 0.0;
    {
        const int nc = (n < XC) ? n : XC;
        for (int k = wid; k < nc; k += 4) {
            double b = (double)bco[k];                       // LDS broadcast
            float2 xj = ((const float2*)xcache[k])[lane];
            ux += b * (double)xj.x;
            uy += b * (double)xj.y;
        }
        for (int k = XC + wid; k < n; k += 4) {
            double b = (double)bco[k];
            float2 xj = ((const float2*)(x + (size_t)list[k] * DD))[lane];
            ux += b * (double)xj.x;
            uy += b * (double)xj.y;
        }
    }
    if (wid) { upx[wid - 1][lane] = ux; upy[wid - 1][lane] = uy; }
    __syncthreads();                                        // [5] partials ready

    // ---- wave 0: combine partials + expmap + mobius_add + proj + store ----
    if (wid == 0) {
        ux += upx[0][lane] + upx[1][lane] + upx[2][lane] + asum * (double)xv2.x;
        uy += upy[0][lane] + upy[1][lane] + upy[2][lane] + asum * (double)xv2.y;

        double p_un2 = ux * ux + uy * uy;
        double p_xu  = (double)xv2.x * ux + (double)xv2.y * uy;
        #pragma unroll
        for (int o = 32; o > 0; o >>= 1) {
            p_un2 += __shfl_xor(p_un2, o, 64);
            p_xu  += __shfl_xor(p_xu,  o, 64);
        }
        double lamfac = fmax(1.0 - x2i, 1e-15);      // 2/lambda_i
        double un = fmax(sqrt(p_un2), 1e-15);
        double th = tanh(un / lamfac);
        double s  = th / un;                         // second = s*u
        double y2 = s * s * p_un2;
        double xy = s * p_xu;
        double c1 = 1.0 + 2.0 * xy + y2;
        double c2 = 1.0 - x2i;
        double den = fmax(1.0 + 2.0 * xy + x2i * y2, 1e-15);
        double ovx = (c1 * (double)xv2.x + c2 * s * ux) / den;
        double ovy = (c1 * (double)xv2.y + c2 * s * uy) / den;

        double p_on2 = ovx * ovx + ovy * ovy;
        #pragma unroll
        for (int o = 32; o > 0; o >>= 1) p_on2 += __shfl_xor(p_on2, o, 64);
        double on = fmax(sqrt(p_on2), 1e-15);
        const double maxn_ = 1.0 - 4e-3;             // (1-PROJ_EPS)/sqrt(c)
        double scale = (on > maxn_) ? (maxn_ / on) : 1.0;
        ((float2*)(out + (size_t)i * DD))[lane] =
            make_float2((float)(ovx * scale), (float)(ovy * scale));
    }
}

extern "C" void kernel_launch(void* const* d_in, const int* in_sizes, int n_in,
                              void* d_out, int out_size, void* d_ws, size_t ws_size,
                              hipStream_t stream) {
    const float* x     = (const float*)d_in[0];
    const float* adj   = (const float*)d_in[1];
    const float* att_w = (const float*)d_in[2];
    const float* att_b = (const float*)d_in[3];
    float* out = (float*)d_out;
    (void)d_ws; (void)ws_size;   // workspace intentionally unused

    hypagg_fused<<<NN, 256, 0, stream>>>(x, adj, att_w, att_b, out);
}

// Round 7
// 67.565 us; speedup vs baseline: 1.1054x; 1.0076x over previous
//
#include <hip/hip_runtime.h>
#include <math.h>

#define NN 768
#define DD 128
#define XC 64     // neighbor rows cached in LDS (binomial(768,0.04): mean~31, max~55)
#define MAXN 128  // compaction capacity: >2x observed max degree

// R7 = exact revert to R4 (best passing config: 68.08 us, absmax 7.8125e-3).
// R5/R6 proved the fp64 pair-math + epilogue is load-bearing for accuracy:
// the reference carries ~7.8e-3 intrinsic f32-chain noise and the threshold
// sits only ~5% above it, so every downstream stage must stay fp64.
__global__ __launch_bounds__(256) void hypagg_fused(
        const float* __restrict__ x, const float* __restrict__ adj,
        const float* __restrict__ att_w, const float* __restrict__ att_b,
        float* __restrict__ out) {
    __shared__ float  xcache[XC][DD];      // 32 KB neighbor-row cache
    __shared__ int    list[MAXN];
    __shared__ float  aval[MAXN];
    __shared__ double dots[MAXN];          // <x_i, x_j>
    __shared__ double y2s[MAXN];           // <x_j, x_j>
    __shared__ double wrs[MAXN];           // <x_j, wr>
    __shared__ float  bco[MAXN];
    __shared__ double upx[3][64];          // aggregation partials, waves 1..3
    __shared__ double upy[3][64];
    __shared__ int    counter;

    const int i = blockIdx.x, t = threadIdx.x;
    const int wid = t >> 6, lane = t & 63;
    const int g = t >> 4, gl = t & 15;     // 16-lane dot groups

    // ---- hoist ALL independent global loads (latency hides under phases 0-1) ----
    float4 adjv = make_float4(0.f, 0.f, 0.f, 0.f);
    if (t >= 64) adjv = ((const float4*)(adj + (size_t)i * NN))[t - 64];
    float2 xv2 = make_float2(0.f, 0.f), wl2 = make_float2(0.f, 0.f);
    if (t < 64) {
        xv2 = ((const float2*)(x + (size_t)i * DD))[lane];   // dims 2l, 2l+1
        wl2 = ((const float2*)att_w)[lane];
    }
    const float4 xa = ((const float4*)(x + (size_t)i * DD))[gl];   // row-i dot frag
    const float4 xb = ((const float4*)(x + (size_t)i * DD))[16 + gl];
    const float4 wa = ((const float4*)(att_w + DD))[gl];           // wr frag
    const float4 wb = ((const float4*)(att_w + DD))[16 + gl];
    const double b0 = (double)att_b[0];

    if (t == 0) counter = 0;
    __syncthreads();                                        // [1] counter ready

    // ---- waves 1..3: compact nonzero columns of adj row i ----
    // ---- wave 0 (concurrently): row scalars x2_i, sL_i (stay in registers) ----
    double x2i = 0.0, sLi = 0.0;
    if (t >= 64) {
        int m = (adjv.x != 0.0f) + (adjv.y != 0.0f) + (adjv.z != 0.0f) + (adjv.w != 0.0f);
        if (m) {
            int base = atomicAdd(&counter, m);
            int j = 4 * (t - 64);
            if (adjv.x != 0.0f && base < MAXN) { list[base] = j;     aval[base] = adjv.x; ++base; }
            if (adjv.y != 0.0f && base < MAXN) { list[base] = j + 1; aval[base] = adjv.y; ++base; }
            if (adjv.z != 0.0f && base < MAXN) { list[base] = j + 2; aval[base] = adjv.z; ++base; }
            if (adjv.w != 0.0f && base < MAXN) { list[base] = j + 3; aval[base] = adjv.w; ++base; }
        }
    } else {
        double dx2 = (double)xv2.x * xv2.x + (double)xv2.y * xv2.y;
        double dl  = (double)xv2.x * wl2.x + (double)xv2.y * wl2.y;
        #pragma unroll
        for (int o = 32; o > 0; o >>= 1) {
            dx2 += __shfl_xor(dx2, o, 64);
            dl  += __shfl_xor(dl,  o, 64);
        }
        x2i = dx2;                                   // all wave-0 lanes hold totals
        double r  = sqrt(dx2);
        double g0 = atanh(fmin(r, 1.0 - 1e-7)) / fmax(r, 1e-15);
        sLi = g0 * dl;
    }
    __syncthreads();                                        // [2] list/aval ready
    const int n = (counter < MAXN) ? counter : MAXN;

    // ---- dot phase: one 16-lane group per neighbor, 8 elems/lane ----
    for (int k = g; k < n; k += 16) {
        const float4* xj4 = (const float4*)(x + (size_t)list[k] * DD);
        float4 a = xj4[gl];        // elems 4gl..4gl+3 (contiguous 256B/group)
        float4 b = xj4[16 + gl];   // elems 64+4gl..
        if (k < XC) {
            ((float4*)xcache[k])[gl]      = a;
            ((float4*)xcache[k])[16 + gl] = b;
        }
        double dd = (double)xa.x * a.x + (double)xa.y * a.y
                  + (double)xa.z * a.z + (double)xa.w * a.w
                  + (double)xb.x * b.x + (double)xb.y * b.y
                  + (double)xb.z * b.z + (double)xb.w * b.w;
        double yy = (double)a.x * a.x + (double)a.y * a.y
                  + (double)a.z * a.z + (double)a.w * a.w
                  + (double)b.x * b.x + (double)b.y * b.y
                  + (double)b.z * b.z + (double)b.w * b.w;
        double ww = (double)wa.x * a.x + (double)wa.y * a.y
                  + (double)wa.z * a.z + (double)wa.w * a.w
                  + (double)wb.x * b.x + (double)wb.y * b.y
                  + (double)wb.z * b.z + (double)wb.w * b.w;
        #pragma unroll
        for (int o = 8; o > 0; o >>= 1) {
            dd += __shfl_down(dd, o, 16);
            yy += __shfl_down(yy, o, 16);
            ww += __shfl_down(ww, o, 16);
        }
        if (gl == 0) { dots[k] = dd; y2s[k] = yy; wrs[k] = ww; }
    }
    __syncthreads();                                        // [3] dots/xcache ready

    // ---- pair math: wave 0 only, one neighbor per lane, fully parallel ----
    double asum = 0.0;
    if (wid == 0) {
        const double beta   = 1.0 - x2i;
        const double factor = fmax(beta, 1e-15);   // 2/(sqrt_c*lambda_i)
        for (int k = lane; k < n; k += 64) {
            double dot = dots[k];
            double y2  = y2s[k];
            double ww  = wrs[k];
            double ry  = sqrt(y2);
            double g0j = atanh(fmin(ry, 1.0 - 1e-7)) / fmax(ry, 1e-15);
            double z   = sLi + g0j * ww + b0;
            double w   = (double)aval[k] / (1.0 + exp(-z));   // sigmoid * adj
            double alpha  = 1.0 - 2.0 * dot + y2;
            double denomc = fmax(1.0 - 2.0 * dot + x2i * y2, 1e-15);
            double sn2 = (alpha * alpha * x2i - 2.0 * alpha * beta * dot + beta * beta * y2)
                         / (denomc * denomc);
            double sn  = fmax(sqrt(fmax(sn2, 0.0)), 1e-15);
            double gg  = atanh(fmin(sn, 1.0 - 1e-7)) / sn;
            double common = w * factor * gg / denomc;
            asum -= common * alpha;              // coefficient on x_i
            bco[k] = (float)(common * beta);     // coefficient on x_j
        }
        #pragma unroll
        for (int o = 32; o > 0; o >>= 1) asum += __shfl_xor(asum, o, 64);
        // all wave-0 lanes now hold total asum (in-register, no LDS)
    }
    __syncthreads();                                        // [4] bco ready

    // ---- aggregation: wave w takes k = w (mod 4); lane owns dims (2l, 2l+1) ----
    double ux = 0.0, uy = 0.0;
    {
        const int nc = (n < XC) ? n : XC;
        for (int k = wid; k < nc; k += 4) {
            double b = (double)bco[k];                       // LDS broadcast
            float2 xj = ((const float2*)xcache[k])[lane];
            ux += b * (double)xj.x;
            uy += b * (double)xj.y;
        }
        for (int k = XC + wid; k < n; k += 4) {
            double b = (double)bco[k];
            float2 xj = ((const float2*)(x + (size_t)list[k] * DD))[lane];
            ux += b * (double)xj.x;
            uy += b * (double)xj.y;
        }
    }
    if (wid) { upx[wid - 1][lane] = ux; upy[wid - 1][lane] = uy; }
    __syncthreads();                                        // [5] partials ready

    // ---- wave 0: combine partials + expmap + mobius_add + proj + store ----
    if (wid == 0) {
        ux += upx[0][lane] + upx[1][lane] + upx[2][lane] + asum * (double)xv2.x;
        uy += upy[0][lane] + upy[1][lane] + upy[2][lane] + asum * (double)xv2.y;

        double p_un2 = ux * ux + uy * uy;
        double p_xu  = (double)xv2.x * ux + (double)xv2.y * uy;
        #pragma unroll
        for (int o = 32; o > 0; o >>= 1) {
            p_un2 += __shfl_xor(p_un2, o, 64);
            p_xu  += __shfl_xor(p_xu,  o, 64);
        }
        double lamfac = fmax(1.0 - x2i, 1e-15);      // 2/lambda_i
        double un = fmax(sqrt(p_un2), 1e-15);
        double th = tanh(un / lamfac);
        double s  = th / un;                         // second = s*u
        double y2 = s * s * p_un2;
        double xy = s * p_xu;
        double c1 = 1.0 + 2.0 * xy + y2;
        double c2 = 1.0 - x2i;
        double den = fmax(1.0 + 2.0 * xy + x2i * y2, 1e-15);
        double ovx = (c1 * (double)xv2.x + c2 * s * ux) / den;
        double ovy = (c1 * (double)xv2.y + c2 * s * uy) / den;

        double p_on2 = ovx * ovx + ovy * ovy;
        #pragma unroll
        for (int o = 32; o > 0; o >>= 1) p_on2 += __shfl_xor(p_on2, o, 64);
        double on = fmax(sqrt(p_on2), 1e-15);
        const double maxn_ = 1.0 - 4e-3;             // (1-PROJ_EPS)/sqrt(c)
        double scale = (on > maxn_) ? (maxn_ / on) : 1.0;
        ((float2*)(out + (size_t)i * DD))[lane] =
            make_float2((float)(ovx * scale), (float)(ovy * scale));
    }
}

extern "C" void kernel_launch(void* const* d_in, const int* in_sizes, int n_in,
                              void* d_out, int out_size, void* d_ws, size_t ws_size,
                              hipStream_t stream) {
    const float* x     = (const float*)d_in[0];
    const float* adj   = (const float*)d_in[1];
    const float* att_w = (const float*)d_in[2];
    const float* att_b = (const float*)d_in[3];
    float* out = (float*)d_out;
    (void)d_ws; (void)ws_size;   // workspace intentionally unused

    hypagg_fused<<<NN, 256, 0, stream>>>(x, adj, att_w, att_b, out);
}